// Round 11
// baseline (80.918 us; speedup 1.0000x reference)
//
#include <hip/hip_runtime.h>
#include <math.h>

#define NN 1024
#define MM 1024
#define DD 256
#define TI 32          // i-rows per block
#define TJ 64          // j-cols per block
#define NTI 32         // i-tiles (col-partial stripes)
#define NTJ 16         // j-tiles (row-partial stripes)
#define PITCH_H 264    // f16 pitch (528 B/row)
#define REP 5          // MEASUREMENT ROUND: 5x compute to split F (overhead) vs C (compute)

typedef _Float16 f16x2 __attribute__((ext_vector_type(2)));
typedef _Float16 f16x4 __attribute__((ext_vector_type(4)));

__device__ inline f16x2 habs2(f16x2 v) {
  unsigned u = __builtin_bit_cast(unsigned, v) & 0x7FFF7FFFu;
  return __builtin_bit_cast(f16x2, u);
}

__device__ inline float dot2acc(f16x2 a, float acc) {
#if __has_builtin(__builtin_amdgcn_fdot2)
  const f16x2 one = {(_Float16)1.0f, (_Float16)1.0f};
  return __builtin_amdgcn_fdot2(a, one, acc, false);
#else
  return acc + (float)a.x + (float)a.y;
#endif
}

__device__ inline void merge_ms(float& m, float& s, float m2, float s2) {
  float mn = fmaxf(m, m2);
  s = s * __expf(m - mn) + s2 * __expf(m2 - mn);
  m = mn;
}

__device__ inline float wredSum(float v) {
#pragma unroll
  for (int o = 32; o > 0; o >>= 1) v += __shfl_down(v, o, 64);
  return v;
}

// ---------------- K1: f16 distance, 32x64 tile, REP'd compute ----------
__global__ __launch_bounds__(256) void k_tile(const float* __restrict__ zx,
                                              const float* __restrict__ zy,
                                              float* __restrict__ S,
                                              float* __restrict__ rowPM,
                                              float* __restrict__ rowPS,
                                              float* __restrict__ colPM,
                                              float* __restrict__ colPS) {
  __shared__ __align__(16) _Float16 xs[TI * PITCH_H];  // 16.5 KiB
  __shared__ __align__(16) _Float16 ys[TJ * PITCH_H];  // 33 KiB
  __shared__ float lm[16][64];                         // 4 KiB
  __shared__ float lsv[16][64];                        // 4 KiB

  const int it = blockIdx.y, jt = blockIdx.x;   // it in [0,32), jt in [0,16)
  const int i0 = it * TI, j0 = jt * TJ;
  const int t = threadIdx.x;
  const int tx = t & 15, ty = t >> 4;

  // stage x: 32 rows x 256 f32 -> f16
#pragma unroll
  for (int k = 0; k < 8; ++k) {
    int idx4 = t + k * 256;
    int r = idx4 >> 6;
    int c4 = idx4 & 63;
    float4 v = reinterpret_cast<const float4*>(zx + (size_t)(i0 + r) * DD)[c4];
    f16x4 h = {(_Float16)v.x, (_Float16)v.y, (_Float16)v.z, (_Float16)v.w};
    *reinterpret_cast<f16x4*>(&xs[r * PITCH_H + c4 * 4]) = h;
  }
  // stage y: 64 rows x 256 f32 -> f16
#pragma unroll
  for (int k = 0; k < 16; ++k) {
    int idx4 = t + k * 256;
    int r = idx4 >> 6;
    int c4 = idx4 & 63;
    float4 v = reinterpret_cast<const float4*>(zy + (size_t)(j0 + r) * DD)[c4];
    f16x4 h = {(_Float16)v.x, (_Float16)v.y, (_Float16)v.z, (_Float16)v.w};
    *reinterpret_cast<f16x4*>(&ys[r * PITCH_H + c4 * 4]) = h;
  }
  __syncthreads();

  // REP'd compute: rep the whole s8 loop; keep-alives defeat DCE; last rep live.
  float acc4[2][4];
  for (int rep = 0; rep < REP; ++rep) {
    float a4[2][4] = {{0.f}};
    for (int s8 = 0; s8 < 32; ++s8) {
      uint4 xw[2], yw[4];
#pragma unroll
      for (int a = 0; a < 2; ++a)
        xw[a] = *reinterpret_cast<const uint4*>(&xs[(ty + a * 16) * PITCH_H + s8 * 8]);
#pragma unroll
      for (int b = 0; b < 4; ++b)
        yw[b] = *reinterpret_cast<const uint4*>(&ys[(tx + b * 16) * PITCH_H + s8 * 8]);
#pragma unroll
      for (int a = 0; a < 2; ++a)
#pragma unroll
        for (int b = 0; b < 4; ++b) {
          float acc = a4[a][b];
          acc = dot2acc(habs2(__builtin_bit_cast(f16x2, xw[a].x) - __builtin_bit_cast(f16x2, yw[b].x)), acc);
          acc = dot2acc(habs2(__builtin_bit_cast(f16x2, xw[a].y) - __builtin_bit_cast(f16x2, yw[b].y)), acc);
          acc = dot2acc(habs2(__builtin_bit_cast(f16x2, xw[a].z) - __builtin_bit_cast(f16x2, yw[b].z)), acc);
          acc = dot2acc(habs2(__builtin_bit_cast(f16x2, xw[a].w) - __builtin_bit_cast(f16x2, yw[b].w)), acc);
          a4[a][b] = acc;
        }
    }
#pragma unroll
    for (int a = 0; a < 2; ++a)
#pragma unroll
      for (int b = 0; b < 4; ++b) {
        asm volatile("" : "+v"(a4[a][b]));  // live + opaque across reps
        acc4[a][b] = a4[a][b];
      }
  }

  // store S tile (f32)
#pragma unroll
  for (int a = 0; a < 2; ++a) {
    int i = i0 + ty + a * 16;
#pragma unroll
    for (int b = 0; b < 4; ++b) {
      int j = j0 + tx + b * 16;
      S[(size_t)i * MM + j] = -acc4[a][b];
    }
  }

  // row partials
#pragma unroll
  for (int a = 0; a < 2; ++a) {
    float m = -acc4[a][0];
#pragma unroll
    for (int b = 1; b < 4; ++b) m = fmaxf(m, -acc4[a][b]);
    float s = 0.f;
#pragma unroll
    for (int b = 0; b < 4; ++b) s += __expf(-acc4[a][b] - m);
#pragma unroll
    for (int off = 1; off < 16; off <<= 1) {
      float m2 = __shfl_xor(m, off, 64);
      float s2 = __shfl_xor(s, off, 64);
      merge_ms(m, s, m2, s2);
    }
    if (tx == 0) {
      int i = i0 + ty + a * 16;
      rowPM[(size_t)jt * NN + i] = m;
      rowPS[(size_t)jt * NN + i] = s;
    }
  }

  // col partials
#pragma unroll
  for (int b = 0; b < 4; ++b) {
    int c = tx + b * 16;
    float m = fmaxf(-acc4[0][b], -acc4[1][b]);
    float s = __expf(-acc4[0][b] - m) + __expf(-acc4[1][b] - m);
    lm[ty][c] = m;
    lsv[ty][c] = s;
  }
  __syncthreads();
  if (t < 64) {
    float m = lm[0][t], s = lsv[0][t];
#pragma unroll
    for (int k = 1; k < 16; ++k) merge_ms(m, s, lm[k][t], lsv[k][t]);
    colPM[(size_t)it * MM + j0 + t] = m;
    colPS[(size_t)it * MM + j0 + t] = s;
  }
}

// ---------------- K2: merge stripe partials -> global stats ----------------
__global__ __launch_bounds__(256) void k_merge(const float* __restrict__ rowPM,
                                               const float* __restrict__ rowPS,
                                               const float* __restrict__ colPM,
                                               const float* __restrict__ colPS,
                                               float* __restrict__ rowM,
                                               float* __restrict__ rowS,
                                               float* __restrict__ colM,
                                               float* __restrict__ colS) {
  int g = blockIdx.x * 256 + threadIdx.x;
  if (g < NN) {
    float m = rowPM[g], s = rowPS[g];
#pragma unroll
    for (int k = 1; k < NTJ; ++k)
      merge_ms(m, s, rowPM[(size_t)k * NN + g], rowPS[(size_t)k * NN + g]);
    rowM[g] = m;
    rowS[g] = s;
  } else {
    int c = g - NN;
    float m = colPM[c], s = colPS[c];
#pragma unroll
    for (int k = 1; k < NTI; ++k)
      merge_ms(m, s, colPM[(size_t)k * MM + c], colPS[(size_t)k * MM + c]);
    colM[c] = m;
    colS[c] = s;
  }
}

// ---------------- K3: weighted accumulation ----------------
__global__ __launch_bounds__(256) void k_accum(const float* __restrict__ S,
                                               const float* __restrict__ rowM,
                                               const float* __restrict__ rowS,
                                               const float* __restrict__ colM,
                                               const float* __restrict__ colS,
                                               float* __restrict__ bNum,
                                               float* __restrict__ bDen) {
  const int i = blockIdx.x;
  const int t = threadIdx.x;
  float4 v = reinterpret_cast<const float4*>(S + (size_t)i * MM)[t];
  const float rm = rowM[i];
  const float rinv = 1.f / rowS[i];
  float4 cm = reinterpret_cast<const float4*>(colM)[t];
  float4 cs = reinterpret_cast<const float4*>(colS)[t];
  float num = 0.f, den = 0.f;
#define DO_COMP(VX, CMX, CSX)               \
  {                                         \
    float a = __expf((VX) - rm) * rinv;     \
    float b = __expf((VX) - (CMX)) / (CSX); \
    float w = a + b - a * b;                \
    num += w * (VX);                        \
    den += w;                               \
  }
  DO_COMP(v.x, cm.x, cs.x)
  DO_COMP(v.y, cm.y, cs.y)
  DO_COMP(v.z, cm.z, cs.z)
  DO_COMP(v.w, cm.w, cs.w)
#undef DO_COMP
  num = wredSum(num);
  den = wredSum(den);
  __shared__ float rn[4], rd[4];
  const int lane = t & 63, wv = t >> 6;
  if (lane == 0) { rn[wv] = num; rd[wv] = den; }
  __syncthreads();
  if (t == 0) {
    bNum[i] = rn[0] + rn[1] + rn[2] + rn[3];
    bDen[i] = rd[0] + rd[1] + rd[2] + rd[3];
  }
}

// ---------------- K4: final reduce + divide ----------------
__global__ __launch_bounds__(256) void k_final(const float* __restrict__ bNum,
                                               const float* __restrict__ bDen,
                                               float* __restrict__ out) {
  const int t = threadIdx.x;
  float4 n4 = reinterpret_cast<const float4*>(bNum)[t];
  float4 d4 = reinterpret_cast<const float4*>(bDen)[t];
  float n = n4.x + n4.y + n4.z + n4.w;
  float d = d4.x + d4.y + d4.z + d4.w;
  n = wredSum(n);
  d = wredSum(d);
  __shared__ float rn[4], rd[4];
  const int lane = t & 63, wv = t >> 6;
  if (lane == 0) { rn[wv] = n; rd[wv] = d; }
  __syncthreads();
  if (t == 0) out[0] = (rn[0] + rn[1] + rn[2] + rn[3]) / (rd[0] + rd[1] + rd[2] + rd[3]);
}

// ---------------- launch ----------------
extern "C" void kernel_launch(void* const* d_in, const int* in_sizes, int n_in,
                              void* d_out, int out_size, void* d_ws, size_t ws_size,
                              hipStream_t stream) {
  const float* zx = (const float*)d_in[0];
  const float* zy = (const float*)d_in[1];
  float* out = (float*)d_out;

  float* ws = (float*)d_ws;
  float* S     = ws;                        // 1M floats
  float* rowPM = S + (size_t)NN * MM;       // NTJ x NN
  float* rowPS = rowPM + NTJ * NN;
  float* colPM = rowPS + NTJ * NN;          // NTI x MM
  float* colPS = colPM + NTI * MM;
  float* rowM  = colPS + NTI * MM;
  float* rowS  = rowM + NN;
  float* colM  = rowS + NN;
  float* colS  = colM + MM;
  float* bNum  = colS + MM;
  float* bDen  = bNum + NN;

  k_tile<<<dim3(NTJ, NTI), 256, 0, stream>>>(zx, zy, S, rowPM, rowPS, colPM, colPS);
  k_merge<<<8, 256, 0, stream>>>(rowPM, rowPS, colPM, colPS, rowM, rowS, colM, colS);
  k_accum<<<NN, 256, 0, stream>>>(S, rowM, rowS, colM, colS, bNum, bDen);
  k_final<<<1, 256, 0, stream>>>(bNum, bDen, out);
}

// Round 12
// 49.036 us; speedup vs baseline: 1.6502x; 1.6502x over previous
//
#include <hip/hip_runtime.h>
#include <math.h>

#define NN 1024
#define MM 1024
#define DD 256
#define TI 32          // i-rows per block
#define TJ 64          // j-cols per block
#define NTI 32         // i-tiles (col-partial stripes)
#define NTJ 16         // j-tiles (row-partial stripes)
#define PITCH_H 264    // f16 pitch (528 B/row)

typedef _Float16 f16x2 __attribute__((ext_vector_type(2)));
typedef _Float16 f16x4 __attribute__((ext_vector_type(4)));

__device__ inline f16x2 habs2(f16x2 v) {
  unsigned u = __builtin_bit_cast(unsigned, v) & 0x7FFF7FFFu;
  return __builtin_bit_cast(f16x2, u);
}

__device__ inline float dot2acc(f16x2 a, float acc) {
#if __has_builtin(__builtin_amdgcn_fdot2)
  const f16x2 one = {(_Float16)1.0f, (_Float16)1.0f};
  return __builtin_amdgcn_fdot2(a, one, acc, false);
#else
  return acc + (float)a.x + (float)a.y;
#endif
}

__device__ inline void merge_ms(float& m, float& s, float m2, float s2) {
  float mn = fmaxf(m, m2);
  s = s * __expf(m - mn) + s2 * __expf(m2 - mn);
  m = mn;
}

__device__ inline float wredSum(float v) {
#pragma unroll
  for (int o = 32; o > 0; o >>= 1) v += __shfl_down(v, o, 64);
  return v;
}

// ---- K1: f16 distance tile + partials + ticket-based stripe merges ----
__global__ __launch_bounds__(256) void k_tile(const float* __restrict__ zx,
                                              const float* __restrict__ zy,
                                              float* __restrict__ S,
                                              float* __restrict__ rowPM,
                                              float* __restrict__ rowPS,
                                              float* __restrict__ colPM,
                                              float* __restrict__ colPS,
                                              float* __restrict__ rowM,
                                              float* __restrict__ rowS,
                                              float* __restrict__ colM,
                                              float* __restrict__ colS,
                                              unsigned* __restrict__ rowCtr,
                                              unsigned* __restrict__ colCtr) {
  __shared__ __align__(16) _Float16 xs[TI * PITCH_H];  // 16.5 KiB
  __shared__ __align__(16) _Float16 ys[TJ * PITCH_H];  // 33 KiB
  __shared__ float lm[16][64];
  __shared__ float lsv[16][64];

  const int it = blockIdx.y, jt = blockIdx.x;   // it in [0,32), jt in [0,16)
  const int i0 = it * TI, j0 = jt * TJ;
  const int t = threadIdx.x;
  const int tx = t & 15, ty = t >> 4;

  // stage x: 32 rows x 256 f32 -> f16
#pragma unroll
  for (int k = 0; k < 8; ++k) {
    int idx4 = t + k * 256;
    int r = idx4 >> 6;
    int c4 = idx4 & 63;
    float4 v = reinterpret_cast<const float4*>(zx + (size_t)(i0 + r) * DD)[c4];
    f16x4 h = {(_Float16)v.x, (_Float16)v.y, (_Float16)v.z, (_Float16)v.w};
    *reinterpret_cast<f16x4*>(&xs[r * PITCH_H + c4 * 4]) = h;
  }
  // stage y: 64 rows x 256 f32 -> f16
#pragma unroll
  for (int k = 0; k < 16; ++k) {
    int idx4 = t + k * 256;
    int r = idx4 >> 6;
    int c4 = idx4 & 63;
    float4 v = reinterpret_cast<const float4*>(zy + (size_t)(j0 + r) * DD)[c4];
    f16x4 h = {(_Float16)v.x, (_Float16)v.y, (_Float16)v.z, (_Float16)v.w};
    *reinterpret_cast<f16x4*>(&ys[r * PITCH_H + c4 * 4]) = h;
  }
  __syncthreads();

  float acc4[2][4] = {{0.f}};
  for (int s8 = 0; s8 < 32; ++s8) {
    uint4 xw[2], yw[4];
#pragma unroll
    for (int a = 0; a < 2; ++a)
      xw[a] = *reinterpret_cast<const uint4*>(&xs[(ty + a * 16) * PITCH_H + s8 * 8]);
#pragma unroll
    for (int b = 0; b < 4; ++b)
      yw[b] = *reinterpret_cast<const uint4*>(&ys[(tx + b * 16) * PITCH_H + s8 * 8]);
#pragma unroll
    for (int a = 0; a < 2; ++a)
#pragma unroll
      for (int b = 0; b < 4; ++b) {
        float acc = acc4[a][b];
        acc = dot2acc(habs2(__builtin_bit_cast(f16x2, xw[a].x) - __builtin_bit_cast(f16x2, yw[b].x)), acc);
        acc = dot2acc(habs2(__builtin_bit_cast(f16x2, xw[a].y) - __builtin_bit_cast(f16x2, yw[b].y)), acc);
        acc = dot2acc(habs2(__builtin_bit_cast(f16x2, xw[a].z) - __builtin_bit_cast(f16x2, yw[b].z)), acc);
        acc = dot2acc(habs2(__builtin_bit_cast(f16x2, xw[a].w) - __builtin_bit_cast(f16x2, yw[b].w)), acc);
        acc4[a][b] = acc;
      }
  }

  // store S tile (f32)
#pragma unroll
  for (int a = 0; a < 2; ++a) {
    int i = i0 + ty + a * 16;
#pragma unroll
    for (int b = 0; b < 4; ++b) {
      int j = j0 + tx + b * 16;
      S[(size_t)i * MM + j] = -acc4[a][b];
    }
  }

  // row partials
#pragma unroll
  for (int a = 0; a < 2; ++a) {
    float m = -acc4[a][0];
#pragma unroll
    for (int b = 1; b < 4; ++b) m = fmaxf(m, -acc4[a][b]);
    float s = 0.f;
#pragma unroll
    for (int b = 0; b < 4; ++b) s += __expf(-acc4[a][b] - m);
#pragma unroll
    for (int off = 1; off < 16; off <<= 1) {
      float m2 = __shfl_xor(m, off, 64);
      float s2 = __shfl_xor(s, off, 64);
      merge_ms(m, s, m2, s2);
    }
    if (tx == 0) {
      int i = i0 + ty + a * 16;
      rowPM[(size_t)jt * NN + i] = m;
      rowPS[(size_t)jt * NN + i] = s;
    }
  }

  // col partials
#pragma unroll
  for (int b = 0; b < 4; ++b) {
    int c = tx + b * 16;
    float m = fmaxf(-acc4[0][b], -acc4[1][b]);
    float s = __expf(-acc4[0][b] - m) + __expf(-acc4[1][b] - m);
    lm[ty][c] = m;
    lsv[ty][c] = s;
  }
  __syncthreads();
  if (t < 64) {
    float m = lm[0][t], s = lsv[0][t];
#pragma unroll
    for (int k = 1; k < 16; ++k) merge_ms(m, s, lm[k][t], lsv[k][t]);
    colPM[(size_t)it * MM + j0 + t] = m;
    colPS[(size_t)it * MM + j0 + t] = s;
  }

  // ---- ticket-based stripe merges (replaces k_merge kernel) ----
  // generation tickets: (old & (N-1)) == N-1 works for ANY counter start value
  // (poison-safe, replay-safe; counters never need resetting).
  __syncthreads();  // all global partial stores issued (barrier drains vmcnt)
  __shared__ int doRow, doCol;
  if (t == 0) {
    __threadfence();  // release our partials (L2 writeback, device scope)
    unsigned o1 = atomicAdd(&rowCtr[it], 1u);
    doRow = ((o1 & (NTJ - 1u)) == (NTJ - 1u)) ? 1 : 0;
    unsigned o2 = atomicAdd(&colCtr[jt], 1u);
    doCol = ((o2 & (NTI - 1u)) == (NTI - 1u)) ? 1 : 0;
  }
  __syncthreads();
  if (doRow) {
    __threadfence();  // acquire other stripes
    if (t < TI) {
      int i = i0 + t;
      float m = rowPM[i], s = rowPS[i];
#pragma unroll
      for (int k = 1; k < NTJ; ++k)
        merge_ms(m, s, rowPM[(size_t)k * NN + i], rowPS[(size_t)k * NN + i]);
      rowM[i] = m;
      rowS[i] = s;
    }
  }
  if (doCol) {
    __threadfence();
    if (t < TJ) {
      int j = j0 + t;
      float m = colPM[j], s = colPS[j];
#pragma unroll
      for (int k = 1; k < NTI; ++k)
        merge_ms(m, s, colPM[(size_t)k * MM + j], colPS[(size_t)k * MM + j]);
      colM[j] = m;
      colS[j] = s;
    }
  }
}

// ---- K2: weighted accumulation + last-block final reduce ----
__global__ __launch_bounds__(256) void k_accum(const float* __restrict__ S,
                                               const float* __restrict__ rowM,
                                               const float* __restrict__ rowS,
                                               const float* __restrict__ colM,
                                               const float* __restrict__ colS,
                                               float* __restrict__ bNum,
                                               float* __restrict__ bDen,
                                               unsigned* __restrict__ accCtr,
                                               float* __restrict__ out) {
  const int bid = blockIdx.x;  // 256 blocks, rows [bid*4, bid*4+4)
  const int t = threadIdx.x;

  // merged col stats (cheap: 8 KB, pre-merged by K1's ticket blocks)
  float4 cm = reinterpret_cast<const float4*>(colM)[t];
  float4 cs = reinterpret_cast<const float4*>(colS)[t];
  float4 ci;
  ci.x = 1.f / cs.x; ci.y = 1.f / cs.y; ci.z = 1.f / cs.z; ci.w = 1.f / cs.w;

  __shared__ float rowMl[4], rowIl[4];
  if (t < 4) {
    int r = bid * 4 + t;
    rowMl[t] = rowM[r];
    rowIl[t] = 1.f / rowS[r];
  }
  __syncthreads();

  float num = 0.f, den = 0.f;
#pragma unroll
  for (int rl = 0; rl < 4; ++rl) {
    int row = bid * 4 + rl;
    float4 v = reinterpret_cast<const float4*>(S + (size_t)row * MM)[t];
    float rm = rowMl[rl], ri = rowIl[rl];
#define DO_COMP(VX, CMX, CIX)                 \
    {                                         \
      float a = __expf((VX) - rm) * ri;       \
      float b = __expf((VX) - (CMX)) * (CIX); \
      float w = a + b - a * b;                \
      num += w * (VX);                        \
      den += w;                               \
    }
    DO_COMP(v.x, cm.x, ci.x)
    DO_COMP(v.y, cm.y, ci.y)
    DO_COMP(v.z, cm.z, ci.z)
    DO_COMP(v.w, cm.w, ci.w)
#undef DO_COMP
  }

  num = wredSum(num);
  den = wredSum(den);
  __shared__ float rn[4], rd[4];
  const int lane = t & 63, wv = t >> 6;
  if (lane == 0) { rn[wv] = num; rd[wv] = den; }
  __syncthreads();
  if (t == 0) {
    bNum[bid] = rn[0] + rn[1] + rn[2] + rn[3];
    bDen[bid] = rd[0] + rd[1] + rd[2] + rd[3];
  }

  // last-block final reduce (generation ticket, poison/replay-safe)
  __shared__ int isLast;
  if (t == 0) {
    __threadfence();
    unsigned old = atomicAdd(accCtr, 1u);
    isLast = ((old & 255u) == 255u) ? 1 : 0;
  }
  __syncthreads();
  if (isLast) {
    __threadfence();
    float n = bNum[t];
    float d = bDen[t];
    n = wredSum(n);
    d = wredSum(d);
    if (lane == 0) { rn[wv] = n; rd[wv] = d; }
    __syncthreads();
    if (t == 0) out[0] = (rn[0] + rn[1] + rn[2] + rn[3]) / (rd[0] + rd[1] + rd[2] + rd[3]);
  }
}

// ---------------- launch ----------------
extern "C" void kernel_launch(void* const* d_in, const int* in_sizes, int n_in,
                              void* d_out, int out_size, void* d_ws, size_t ws_size,
                              hipStream_t stream) {
  const float* zx = (const float*)d_in[0];
  const float* zy = (const float*)d_in[1];
  float* out = (float*)d_out;

  float* ws = (float*)d_ws;
  float* S     = ws;                        // 1M floats
  float* rowPM = S + (size_t)NN * MM;       // NTJ x NN
  float* rowPS = rowPM + NTJ * NN;
  float* colPM = rowPS + NTJ * NN;          // NTI x MM
  float* colPS = colPM + NTI * MM;
  float* rowM  = colPS + NTI * MM;
  float* rowS  = rowM + NN;
  float* colM  = rowS + NN;
  float* colS  = colM + MM;
  float* bNum  = colS + MM;                 // 256
  float* bDen  = bNum + 256;                // 256
  unsigned* rowCtr = (unsigned*)(bDen + 256);  // 32
  unsigned* colCtr = rowCtr + NTI;             // 16
  unsigned* accCtr = colCtr + NTJ;             // 1

  k_tile<<<dim3(NTJ, NTI), 256, 0, stream>>>(zx, zy, S, rowPM, rowPS, colPM, colPS,
                                             rowM, rowS, colM, colS, rowCtr, colCtr);
  k_accum<<<256, 256, 0, stream>>>(S, rowM, rowS, colM, colS, bNum, bDen, accCtr, out);
}

// Round 13
// 44.059 us; speedup vs baseline: 1.8366x; 1.1129x over previous
//
#include <hip/hip_runtime.h>
#include <math.h>

#define NN 1024
#define MM 1024
#define DD 256
#define TI 32          // i-rows per block
#define TJ 64          // j-cols per block
#define NTI 32         // i-tiles (col-partial stripes)
#define NTJ 16         // j-tiles (row-partial stripes)
#define PITCH_H 264    // f16 pitch (528 B/row): x broadcast, y 2-way (free)
#define NTHR 128       // 2 waves/block, 4x4 per-thread tile

typedef _Float16 f16x2 __attribute__((ext_vector_type(2)));
typedef _Float16 f16x4 __attribute__((ext_vector_type(4)));

__device__ inline f16x2 habs2(f16x2 v) {
  unsigned u = __builtin_bit_cast(unsigned, v) & 0x7FFF7FFFu;
  return __builtin_bit_cast(f16x2, u);
}

__device__ inline float dot2acc(f16x2 a, float acc) {
#if __has_builtin(__builtin_amdgcn_fdot2)
  const f16x2 one = {(_Float16)1.0f, (_Float16)1.0f};
  return __builtin_amdgcn_fdot2(a, one, acc, false);
#else
  return acc + (float)a.x + (float)a.y;
#endif
}

__device__ inline void merge_ms(float& m, float& s, float m2, float s2) {
  float mn = fmaxf(m, m2);
  s = s * __expf(m - mn) + s2 * __expf(m2 - mn);
  m = mn;
}

__device__ inline float wredSum(float v) {
#pragma unroll
  for (int o = 32; o > 0; o >>= 1) v += __shfl_down(v, o, 64);
  return v;
}

// ---- K1: f16 distance, 32x64 block tile, 128 thr, 4x4 per-thread ----
__global__ __launch_bounds__(NTHR) void k_tile(const float* __restrict__ zx,
                                               const float* __restrict__ zy,
                                               float* __restrict__ S,
                                               float* __restrict__ rowPM,
                                               float* __restrict__ rowPS,
                                               float* __restrict__ colPM,
                                               float* __restrict__ colPS) {
  // 50688 B staging; partial arrays alias the xs region after compute.
  __shared__ __align__(16) unsigned char smem[(TI + TJ) * PITCH_H * 2];
  _Float16* xs = reinterpret_cast<_Float16*>(smem);                    // 16896 B
  _Float16* ys = reinterpret_cast<_Float16*>(smem + TI * PITCH_H * 2); // 33792 B
  float* lmb = reinterpret_cast<float*>(smem);        // [8][64] aliases xs
  float* lsb = lmb + 8 * 64;                          // [8][64]

  const int it = blockIdx.y, jt = blockIdx.x;   // it in [0,32), jt in [0,16)
  const int i0 = it * TI, j0 = jt * TJ;
  const int t = threadIdx.x;                    // 0..127
  const int tx = t & 15, ty = t >> 4;           // ty in [0,8)

  // stage x: 32 rows x 64 float4 = 2048 float4, 16/thread, coalesced
#pragma unroll
  for (int k = 0; k < 16; ++k) {
    int idx4 = t + k * NTHR;
    int r = idx4 >> 6;
    int c4 = idx4 & 63;
    float4 v = reinterpret_cast<const float4*>(zx + (size_t)(i0 + r) * DD)[c4];
    f16x4 h = {(_Float16)v.x, (_Float16)v.y, (_Float16)v.z, (_Float16)v.w};
    *reinterpret_cast<f16x4*>(&xs[r * PITCH_H + c4 * 4]) = h;
  }
  // stage y: 64 rows x 64 float4 = 4096 float4, 32/thread
#pragma unroll
  for (int k = 0; k < 32; ++k) {
    int idx4 = t + k * NTHR;
    int r = idx4 >> 6;
    int c4 = idx4 & 63;
    float4 v = reinterpret_cast<const float4*>(zy + (size_t)(j0 + r) * DD)[c4];
    f16x4 h = {(_Float16)v.x, (_Float16)v.y, (_Float16)v.z, (_Float16)v.w};
    *reinterpret_cast<f16x4*>(&ys[r * PITCH_H + c4 * 4]) = h;
  }
  __syncthreads();

  // rows i0 + ty + a*8 (a<4), cols j0 + tx + b*16 (b<4)
  float acc4[4][4] = {{0.f}};
  for (int s8 = 0; s8 < 32; ++s8) {
    uint4 xw[4], yw[4];
#pragma unroll
    for (int a = 0; a < 4; ++a)
      xw[a] = *reinterpret_cast<const uint4*>(&xs[(ty + a * 8) * PITCH_H + s8 * 8]);
#pragma unroll
    for (int b = 0; b < 4; ++b)
      yw[b] = *reinterpret_cast<const uint4*>(&ys[(tx + b * 16) * PITCH_H + s8 * 8]);
#pragma unroll
    for (int a = 0; a < 4; ++a)
#pragma unroll
      for (int b = 0; b < 4; ++b) {
        float acc = acc4[a][b];
        acc = dot2acc(habs2(__builtin_bit_cast(f16x2, xw[a].x) - __builtin_bit_cast(f16x2, yw[b].x)), acc);
        acc = dot2acc(habs2(__builtin_bit_cast(f16x2, xw[a].y) - __builtin_bit_cast(f16x2, yw[b].y)), acc);
        acc = dot2acc(habs2(__builtin_bit_cast(f16x2, xw[a].z) - __builtin_bit_cast(f16x2, yw[b].z)), acc);
        acc = dot2acc(habs2(__builtin_bit_cast(f16x2, xw[a].w) - __builtin_bit_cast(f16x2, yw[b].w)), acc);
        acc4[a][b] = acc;
      }
  }

  // store S tile (f32)
#pragma unroll
  for (int a = 0; a < 4; ++a) {
    int i = i0 + ty + a * 8;
#pragma unroll
    for (int b = 0; b < 4; ++b) {
      int j = j0 + tx + b * 16;
      S[(size_t)i * MM + j] = -acc4[a][b];
    }
  }

  // row partials: row i = i0+ty+a*8, reduce over b regs + tx lanes (16-lane groups)
#pragma unroll
  for (int a = 0; a < 4; ++a) {
    float m = -acc4[a][0];
#pragma unroll
    for (int b = 1; b < 4; ++b) m = fmaxf(m, -acc4[a][b]);
    float s = 0.f;
#pragma unroll
    for (int b = 0; b < 4; ++b) s += __expf(-acc4[a][b] - m);
#pragma unroll
    for (int off = 1; off < 16; off <<= 1) {
      float m2 = __shfl_xor(m, off, 64);
      float s2 = __shfl_xor(s, off, 64);
      merge_ms(m, s, m2, s2);
    }
    if (tx == 0) {
      int i = i0 + ty + a * 8;
      rowPM[(size_t)jt * NN + i] = m;
      rowPS[(size_t)jt * NN + i] = s;
    }
  }

  // col partials: all waves done reading xs -> safe to alias lmb/lsb onto it
  __syncthreads();
#pragma unroll
  for (int b = 0; b < 4; ++b) {
    int c = tx + b * 16;
    float m = -acc4[0][b];
#pragma unroll
    for (int a = 1; a < 4; ++a) m = fmaxf(m, -acc4[a][b]);
    float s = 0.f;
#pragma unroll
    for (int a = 0; a < 4; ++a) s += __expf(-acc4[a][b] - m);
    lmb[ty * 64 + c] = m;
    lsb[ty * 64 + c] = s;
  }
  __syncthreads();
  if (t < 64) {
    float m = lmb[t], s = lsb[t];
#pragma unroll
    for (int k = 1; k < 8; ++k) merge_ms(m, s, lmb[k * 64 + t], lsb[k * 64 + t]);
    colPM[(size_t)it * MM + j0 + t] = m;
    colPS[(size_t)it * MM + j0 + t] = s;
  }
}

// ---- K2: merge stripe partials -> global stats (R10-proven, fence-free) ----
__global__ __launch_bounds__(256) void k_merge(const float* __restrict__ rowPM,
                                               const float* __restrict__ rowPS,
                                               const float* __restrict__ colPM,
                                               const float* __restrict__ colPS,
                                               float* __restrict__ rowM,
                                               float* __restrict__ rowS,
                                               float* __restrict__ colM,
                                               float* __restrict__ colS) {
  int g = blockIdx.x * 256 + threadIdx.x;
  if (g < NN) {
    float m = rowPM[g], s = rowPS[g];
#pragma unroll
    for (int k = 1; k < NTJ; ++k)
      merge_ms(m, s, rowPM[(size_t)k * NN + g], rowPS[(size_t)k * NN + g]);
    rowM[g] = m;
    rowS[g] = s;
  } else {
    int c = g - NN;
    float m = colPM[c], s = colPS[c];
#pragma unroll
    for (int k = 1; k < NTI; ++k)
      merge_ms(m, s, colPM[(size_t)k * MM + c], colPS[(size_t)k * MM + c]);
    colM[c] = m;
    colS[c] = s;
  }
}

// ---- K3: weighted accumulation (R10-proven) ----
__global__ __launch_bounds__(256) void k_accum(const float* __restrict__ S,
                                               const float* __restrict__ rowM,
                                               const float* __restrict__ rowS,
                                               const float* __restrict__ colM,
                                               const float* __restrict__ colS,
                                               float* __restrict__ bNum,
                                               float* __restrict__ bDen) {
  const int i = blockIdx.x;
  const int t = threadIdx.x;
  float4 v = reinterpret_cast<const float4*>(S + (size_t)i * MM)[t];
  const float rm = rowM[i];
  const float rinv = 1.f / rowS[i];
  float4 cm = reinterpret_cast<const float4*>(colM)[t];
  float4 cs = reinterpret_cast<const float4*>(colS)[t];
  float num = 0.f, den = 0.f;
#define DO_COMP(VX, CMX, CSX)               \
  {                                         \
    float a = __expf((VX) - rm) * rinv;     \
    float b = __expf((VX) - (CMX)) / (CSX); \
    float w = a + b - a * b;                \
    num += w * (VX);                        \
    den += w;                               \
  }
  DO_COMP(v.x, cm.x, cs.x)
  DO_COMP(v.y, cm.y, cs.y)
  DO_COMP(v.z, cm.z, cs.z)
  DO_COMP(v.w, cm.w, cs.w)
#undef DO_COMP
  num = wredSum(num);
  den = wredSum(den);
  __shared__ float rn[4], rd[4];
  const int lane = t & 63, wv = t >> 6;
  if (lane == 0) { rn[wv] = num; rd[wv] = den; }
  __syncthreads();
  if (t == 0) {
    bNum[i] = rn[0] + rn[1] + rn[2] + rn[3];
    bDen[i] = rd[0] + rd[1] + rd[2] + rd[3];
  }
}

// ---- K4: final reduce + divide (R10-proven) ----
__global__ __launch_bounds__(256) void k_final(const float* __restrict__ bNum,
                                               const float* __restrict__ bDen,
                                               float* __restrict__ out) {
  const int t = threadIdx.x;
  float4 n4 = reinterpret_cast<const float4*>(bNum)[t];
  float4 d4 = reinterpret_cast<const float4*>(bDen)[t];
  float n = n4.x + n4.y + n4.z + n4.w;
  float d = d4.x + d4.y + d4.z + d4.w;
  n = wredSum(n);
  d = wredSum(d);
  __shared__ float rn[4], rd[4];
  const int lane = t & 63, wv = t >> 6;
  if (lane == 0) { rn[wv] = n; rd[wv] = d; }
  __syncthreads();
  if (t == 0) out[0] = (rn[0] + rn[1] + rn[2] + rn[3]) / (rd[0] + rd[1] + rd[2] + rd[3]);
}

// ---------------- launch ----------------
extern "C" void kernel_launch(void* const* d_in, const int* in_sizes, int n_in,
                              void* d_out, int out_size, void* d_ws, size_t ws_size,
                              hipStream_t stream) {
  const float* zx = (const float*)d_in[0];
  const float* zy = (const float*)d_in[1];
  float* out = (float*)d_out;

  float* ws = (float*)d_ws;
  float* S     = ws;                        // 1M floats
  float* rowPM = S + (size_t)NN * MM;       // NTJ x NN
  float* rowPS = rowPM + NTJ * NN;
  float* colPM = rowPS + NTJ * NN;          // NTI x MM
  float* colPS = colPM + NTI * MM;
  float* rowM  = colPS + NTI * MM;
  float* rowS  = rowM + NN;
  float* colM  = rowS + NN;
  float* colS  = colM + MM;
  float* bNum  = colS + MM;
  float* bDen  = bNum + NN;

  k_tile<<<dim3(NTJ, NTI), NTHR, 0, stream>>>(zx, zy, S, rowPM, rowPS, colPM, colPS);
  k_merge<<<8, 256, 0, stream>>>(rowPM, rowPS, colPM, colPS, rowM, rowS, colM, colS);
  k_accum<<<NN, 256, 0, stream>>>(S, rowM, rowS, colM, colS, bNum, bDen);
  k_final<<<1, 256, 0, stream>>>(bNum, bDen, out);
}

// Round 14
// 37.878 us; speedup vs baseline: 2.1362x; 1.1632x over previous
//
#include <hip/hip_runtime.h>
#include <math.h>

#define NN 1024
#define MM 1024
#define DD 256
#define TI 32          // i-rows per block
#define TJ 64          // j-cols per block
#define NTI 32         // i-tiles (col-partial stripes)
#define NTJ 16         // j-tiles (row-partial stripes)
#define PITCH_H 264    // f16 pitch (528 B/row)

typedef _Float16 f16x2 __attribute__((ext_vector_type(2)));
typedef _Float16 f16x4 __attribute__((ext_vector_type(4)));

__device__ inline f16x2 habs2(f16x2 v) {
  unsigned u = __builtin_bit_cast(unsigned, v) & 0x7FFF7FFFu;
  return __builtin_bit_cast(f16x2, u);
}

__device__ inline float dot2acc(f16x2 a, float acc) {
#if __has_builtin(__builtin_amdgcn_fdot2)
  const f16x2 one = {(_Float16)1.0f, (_Float16)1.0f};
  return __builtin_amdgcn_fdot2(a, one, acc, false);
#else
  return acc + (float)a.x + (float)a.y;
#endif
}

__device__ inline void merge_ms(float& m, float& s, float m2, float s2) {
  float mn = fmaxf(m, m2);
  s = s * __expf(m - mn) + s2 * __expf(m2 - mn);
  m = mn;
}

__device__ inline float wredSum(float v) {
#pragma unroll
  for (int o = 32; o > 0; o >>= 1) v += __shfl_down(v, o, 64);
  return v;
}

// ---- K1: f16 distance, 32x64 tile, 512 blocks (2/CU, 8 waves/CU) — R10 EXACT ----
__global__ __launch_bounds__(256) void k_tile(const float* __restrict__ zx,
                                              const float* __restrict__ zy,
                                              float* __restrict__ S,
                                              float* __restrict__ rowPM,
                                              float* __restrict__ rowPS,
                                              float* __restrict__ colPM,
                                              float* __restrict__ colPS) {
  __shared__ __align__(16) _Float16 xs[TI * PITCH_H];  // 16.5 KiB
  __shared__ __align__(16) _Float16 ys[TJ * PITCH_H];  // 33 KiB
  __shared__ float lm[16][64];
  __shared__ float lsv[16][64];

  const int it = blockIdx.y, jt = blockIdx.x;   // it in [0,32), jt in [0,16)
  const int i0 = it * TI, j0 = jt * TJ;
  const int t = threadIdx.x;
  const int tx = t & 15, ty = t >> 4;

  // stage x: 32 rows x 256 f32 -> f16
#pragma unroll
  for (int k = 0; k < 8; ++k) {
    int idx4 = t + k * 256;
    int r = idx4 >> 6;
    int c4 = idx4 & 63;
    float4 v = reinterpret_cast<const float4*>(zx + (size_t)(i0 + r) * DD)[c4];
    f16x4 h = {(_Float16)v.x, (_Float16)v.y, (_Float16)v.z, (_Float16)v.w};
    *reinterpret_cast<f16x4*>(&xs[r * PITCH_H + c4 * 4]) = h;
  }
  // stage y: 64 rows x 256 f32 -> f16
#pragma unroll
  for (int k = 0; k < 16; ++k) {
    int idx4 = t + k * 256;
    int r = idx4 >> 6;
    int c4 = idx4 & 63;
    float4 v = reinterpret_cast<const float4*>(zy + (size_t)(j0 + r) * DD)[c4];
    f16x4 h = {(_Float16)v.x, (_Float16)v.y, (_Float16)v.z, (_Float16)v.w};
    *reinterpret_cast<f16x4*>(&ys[r * PITCH_H + c4 * 4]) = h;
  }
  __syncthreads();

  float acc4[2][4] = {{0.f}};
  for (int s8 = 0; s8 < 32; ++s8) {
    uint4 xw[2], yw[4];
#pragma unroll
    for (int a = 0; a < 2; ++a)
      xw[a] = *reinterpret_cast<const uint4*>(&xs[(ty + a * 16) * PITCH_H + s8 * 8]);
#pragma unroll
    for (int b = 0; b < 4; ++b)
      yw[b] = *reinterpret_cast<const uint4*>(&ys[(tx + b * 16) * PITCH_H + s8 * 8]);
#pragma unroll
    for (int a = 0; a < 2; ++a)
#pragma unroll
      for (int b = 0; b < 4; ++b) {
        float acc = acc4[a][b];
        acc = dot2acc(habs2(__builtin_bit_cast(f16x2, xw[a].x) - __builtin_bit_cast(f16x2, yw[b].x)), acc);
        acc = dot2acc(habs2(__builtin_bit_cast(f16x2, xw[a].y) - __builtin_bit_cast(f16x2, yw[b].y)), acc);
        acc = dot2acc(habs2(__builtin_bit_cast(f16x2, xw[a].z) - __builtin_bit_cast(f16x2, yw[b].z)), acc);
        acc = dot2acc(habs2(__builtin_bit_cast(f16x2, xw[a].w) - __builtin_bit_cast(f16x2, yw[b].w)), acc);
        acc4[a][b] = acc;
      }
  }

  // store S tile (f32)
#pragma unroll
  for (int a = 0; a < 2; ++a) {
    int i = i0 + ty + a * 16;
#pragma unroll
    for (int b = 0; b < 4; ++b) {
      int j = j0 + tx + b * 16;
      S[(size_t)i * MM + j] = -acc4[a][b];
    }
  }

  // row partials
#pragma unroll
  for (int a = 0; a < 2; ++a) {
    float m = -acc4[a][0];
#pragma unroll
    for (int b = 1; b < 4; ++b) m = fmaxf(m, -acc4[a][b]);
    float s = 0.f;
#pragma unroll
    for (int b = 0; b < 4; ++b) s += __expf(-acc4[a][b] - m);
#pragma unroll
    for (int off = 1; off < 16; off <<= 1) {
      float m2 = __shfl_xor(m, off, 64);
      float s2 = __shfl_xor(s, off, 64);
      merge_ms(m, s, m2, s2);
    }
    if (tx == 0) {
      int i = i0 + ty + a * 16;
      rowPM[(size_t)jt * NN + i] = m;
      rowPS[(size_t)jt * NN + i] = s;
    }
  }

  // col partials
#pragma unroll
  for (int b = 0; b < 4; ++b) {
    int c = tx + b * 16;
    float m = fmaxf(-acc4[0][b], -acc4[1][b]);
    float s = __expf(-acc4[0][b] - m) + __expf(-acc4[1][b] - m);
    lm[ty][c] = m;
    lsv[ty][c] = s;
  }
  __syncthreads();
  if (t < 64) {
    float m = lm[0][t], s = lsv[0][t];
#pragma unroll
    for (int k = 1; k < 16; ++k) merge_ms(m, s, lm[k][t], lsv[k][t]);
    colPM[(size_t)it * MM + j0 + t] = m;
    colPS[(size_t)it * MM + j0 + t] = s;
  }
}

// ---- K2: fused merge + weighted accumulation (fence-free) ----
// 256 blocks x 4 rows. Col stats re-merged per block (duplicate work, parallel,
// ~1 us); stripe partials were written by the PREVIOUS kernel -> stream order
// guarantees visibility, no fences needed.
__global__ __launch_bounds__(256) void k_macc(const float* __restrict__ S,
                                              const float* __restrict__ rowPM,
                                              const float* __restrict__ rowPS,
                                              const float* __restrict__ colPM,
                                              const float* __restrict__ colPS,
                                              float* __restrict__ bNum,
                                              float* __restrict__ bDen) {
  const int bid = blockIdx.x;  // rows [bid*4, bid*4+4)
  const int t = threadIdx.x;

  // col stats for cols 4t..4t+3: merge 32 stripes in registers
  float4 cm = reinterpret_cast<const float4*>(colPM)[t];
  float4 cs = reinterpret_cast<const float4*>(colPS)[t];
#pragma unroll
  for (int k = 1; k < NTI; ++k) {
    float4 m2 = reinterpret_cast<const float4*>(colPM + (size_t)k * MM)[t];
    float4 s2 = reinterpret_cast<const float4*>(colPS + (size_t)k * MM)[t];
    merge_ms(cm.x, cs.x, m2.x, s2.x);
    merge_ms(cm.y, cs.y, m2.y, s2.y);
    merge_ms(cm.z, cs.z, m2.z, s2.z);
    merge_ms(cm.w, cs.w, m2.w, s2.w);
  }
  float4 ci;
  ci.x = 1.f / cs.x; ci.y = 1.f / cs.y; ci.z = 1.f / cs.z; ci.w = 1.f / cs.w;

  // row stats for this block's 4 rows: merge 16 stripes
  __shared__ float rowMl[4], rowIl[4];
  if (t < 4) {
    int r = bid * 4 + t;
    float m = rowPM[r], s = rowPS[r];
#pragma unroll
    for (int k = 1; k < NTJ; ++k)
      merge_ms(m, s, rowPM[(size_t)k * NN + r], rowPS[(size_t)k * NN + r]);
    rowMl[t] = m;
    rowIl[t] = 1.f / s;
  }
  __syncthreads();

  // weighted accumulation over 4 rows x 1024 cols
  float num = 0.f, den = 0.f;
#pragma unroll
  for (int rl = 0; rl < 4; ++rl) {
    int row = bid * 4 + rl;
    float4 v = reinterpret_cast<const float4*>(S + (size_t)row * MM)[t];
    float rm = rowMl[rl], ri = rowIl[rl];
#define DO_COMP(VX, CMX, CIX)                 \
    {                                         \
      float a = __expf((VX) - rm) * ri;       \
      float b = __expf((VX) - (CMX)) * (CIX); \
      float w = a + b - a * b;                \
      num += w * (VX);                        \
      den += w;                               \
    }
    DO_COMP(v.x, cm.x, ci.x)
    DO_COMP(v.y, cm.y, ci.y)
    DO_COMP(v.z, cm.z, ci.z)
    DO_COMP(v.w, cm.w, ci.w)
#undef DO_COMP
  }

  num = wredSum(num);
  den = wredSum(den);
  __shared__ float rn[4], rd[4];
  const int lane = t & 63, wv = t >> 6;
  if (lane == 0) { rn[wv] = num; rd[wv] = den; }
  __syncthreads();
  if (t == 0) {
    bNum[bid] = rn[0] + rn[1] + rn[2] + rn[3];
    bDen[bid] = rd[0] + rd[1] + rd[2] + rd[3];
  }
}

// ---- K3: final reduce + divide (R10-proven) ----
__global__ __launch_bounds__(256) void k_final(const float* __restrict__ bNum,
                                               const float* __restrict__ bDen,
                                               float* __restrict__ out) {
  const int t = threadIdx.x;
  // 256 entries: one per thread
  float n = bNum[t];
  float d = bDen[t];
  n = wredSum(n);
  d = wredSum(d);
  __shared__ float rn[4], rd[4];
  const int lane = t & 63, wv = t >> 6;
  if (lane == 0) { rn[wv] = n; rd[wv] = d; }
  __syncthreads();
  if (t == 0) out[0] = (rn[0] + rn[1] + rn[2] + rn[3]) / (rd[0] + rd[1] + rd[2] + rd[3]);
}

// ---------------- launch ----------------
extern "C" void kernel_launch(void* const* d_in, const int* in_sizes, int n_in,
                              void* d_out, int out_size, void* d_ws, size_t ws_size,
                              hipStream_t stream) {
  const float* zx = (const float*)d_in[0];
  const float* zy = (const float*)d_in[1];
  float* out = (float*)d_out;

  float* ws = (float*)d_ws;
  float* S     = ws;                        // 1M floats
  float* rowPM = S + (size_t)NN * MM;       // NTJ x NN
  float* rowPS = rowPM + NTJ * NN;
  float* colPM = rowPS + NTJ * NN;          // NTI x MM
  float* colPS = colPM + NTI * MM;
  float* bNum  = colPS + NTI * MM;          // 256
  float* bDen  = bNum + 256;                // 256

  k_tile<<<dim3(NTJ, NTI), 256, 0, stream>>>(zx, zy, S, rowPM, rowPS, colPM, colPS);
  k_macc<<<256, 256, 0, stream>>>(S, rowPM, rowPS, colPM, colPS, bNum, bDen);
  k_final<<<1, 256, 0, stream>>>(bNum, bDen, out);
}

// Round 15
// 31.931 us; speedup vs baseline: 2.5341x; 1.1862x over previous
//
#include <hip/hip_runtime.h>
#include <math.h>

#define NN 1024
#define MM 1024
#define DD 256
#define TI 32          // i-rows per block
#define TJ 64          // j-cols per block
#define NTI 32         // i-tiles (col-partial stripes)
#define NTJ 16         // j-tiles (row-partial stripes)
#define PITCH_H 264    // f16 pitch (528 B/row)

typedef _Float16 f16x2 __attribute__((ext_vector_type(2)));
typedef _Float16 f16x4 __attribute__((ext_vector_type(4)));

__device__ inline f16x2 habs2(f16x2 v) {
  unsigned u = __builtin_bit_cast(unsigned, v) & 0x7FFF7FFFu;
  return __builtin_bit_cast(f16x2, u);
}

__device__ inline float dot2acc(f16x2 a, float acc) {
#if __has_builtin(__builtin_amdgcn_fdot2)
  const f16x2 one = {(_Float16)1.0f, (_Float16)1.0f};
  return __builtin_amdgcn_fdot2(a, one, acc, false);
#else
  return acc + (float)a.x + (float)a.y;
#endif
}

__device__ inline void merge_ms(float& m, float& s, float m2, float s2) {
  float mn = fmaxf(m, m2);
  s = s * __expf(m - mn) + s2 * __expf(m2 - mn);
  m = mn;
}

__device__ inline float wredSum(float v) {
#pragma unroll
  for (int o = 32; o > 0; o >>= 1) v += __shfl_down(v, o, 64);
  return v;
}

// ---- K1: f16 distance, 32x64 tile, 512 blocks (2/CU, 8 waves/CU) — R10 EXACT ----
__global__ __launch_bounds__(256) void k_tile(const float* __restrict__ zx,
                                              const float* __restrict__ zy,
                                              float* __restrict__ S,
                                              float* __restrict__ rowPM,
                                              float* __restrict__ rowPS,
                                              float* __restrict__ colPM,
                                              float* __restrict__ colPS) {
  __shared__ __align__(16) _Float16 xs[TI * PITCH_H];  // 16.5 KiB
  __shared__ __align__(16) _Float16 ys[TJ * PITCH_H];  // 33 KiB
  __shared__ float lm[16][64];
  __shared__ float lsv[16][64];

  const int it = blockIdx.y, jt = blockIdx.x;   // it in [0,32), jt in [0,16)
  const int i0 = it * TI, j0 = jt * TJ;
  const int t = threadIdx.x;
  const int tx = t & 15, ty = t >> 4;

  // stage x: 32 rows x 256 f32 -> f16
#pragma unroll
  for (int k = 0; k < 8; ++k) {
    int idx4 = t + k * 256;
    int r = idx4 >> 6;
    int c4 = idx4 & 63;
    float4 v = reinterpret_cast<const float4*>(zx + (size_t)(i0 + r) * DD)[c4];
    f16x4 h = {(_Float16)v.x, (_Float16)v.y, (_Float16)v.z, (_Float16)v.w};
    *reinterpret_cast<f16x4*>(&xs[r * PITCH_H + c4 * 4]) = h;
  }
  // stage y: 64 rows x 256 f32 -> f16
#pragma unroll
  for (int k = 0; k < 16; ++k) {
    int idx4 = t + k * 256;
    int r = idx4 >> 6;
    int c4 = idx4 & 63;
    float4 v = reinterpret_cast<const float4*>(zy + (size_t)(j0 + r) * DD)[c4];
    f16x4 h = {(_Float16)v.x, (_Float16)v.y, (_Float16)v.z, (_Float16)v.w};
    *reinterpret_cast<f16x4*>(&ys[r * PITCH_H + c4 * 4]) = h;
  }
  __syncthreads();

  float acc4[2][4] = {{0.f}};
  for (int s8 = 0; s8 < 32; ++s8) {
    uint4 xw[2], yw[4];
#pragma unroll
    for (int a = 0; a < 2; ++a)
      xw[a] = *reinterpret_cast<const uint4*>(&xs[(ty + a * 16) * PITCH_H + s8 * 8]);
#pragma unroll
    for (int b = 0; b < 4; ++b)
      yw[b] = *reinterpret_cast<const uint4*>(&ys[(tx + b * 16) * PITCH_H + s8 * 8]);
#pragma unroll
    for (int a = 0; a < 2; ++a)
#pragma unroll
      for (int b = 0; b < 4; ++b) {
        float acc = acc4[a][b];
        acc = dot2acc(habs2(__builtin_bit_cast(f16x2, xw[a].x) - __builtin_bit_cast(f16x2, yw[b].x)), acc);
        acc = dot2acc(habs2(__builtin_bit_cast(f16x2, xw[a].y) - __builtin_bit_cast(f16x2, yw[b].y)), acc);
        acc = dot2acc(habs2(__builtin_bit_cast(f16x2, xw[a].z) - __builtin_bit_cast(f16x2, yw[b].z)), acc);
        acc = dot2acc(habs2(__builtin_bit_cast(f16x2, xw[a].w) - __builtin_bit_cast(f16x2, yw[b].w)), acc);
        acc4[a][b] = acc;
      }
  }

  // store S tile (f32)
#pragma unroll
  for (int a = 0; a < 2; ++a) {
    int i = i0 + ty + a * 16;
#pragma unroll
    for (int b = 0; b < 4; ++b) {
      int j = j0 + tx + b * 16;
      S[(size_t)i * MM + j] = -acc4[a][b];
    }
  }

  // row partials
#pragma unroll
  for (int a = 0; a < 2; ++a) {
    float m = -acc4[a][0];
#pragma unroll
    for (int b = 1; b < 4; ++b) m = fmaxf(m, -acc4[a][b]);
    float s = 0.f;
#pragma unroll
    for (int b = 0; b < 4; ++b) s += __expf(-acc4[a][b] - m);
#pragma unroll
    for (int off = 1; off < 16; off <<= 1) {
      float m2 = __shfl_xor(m, off, 64);
      float s2 = __shfl_xor(s, off, 64);
      merge_ms(m, s, m2, s2);
    }
    if (tx == 0) {
      int i = i0 + ty + a * 16;
      rowPM[(size_t)jt * NN + i] = m;
      rowPS[(size_t)jt * NN + i] = s;
    }
  }

  // col partials
#pragma unroll
  for (int b = 0; b < 4; ++b) {
    int c = tx + b * 16;
    float m = fmaxf(-acc4[0][b], -acc4[1][b]);
    float s = __expf(-acc4[0][b] - m) + __expf(-acc4[1][b] - m);
    lm[ty][c] = m;
    lsv[ty][c] = s;
  }
  __syncthreads();
  if (t < 64) {
    float m = lm[0][t], s = lsv[0][t];
#pragma unroll
    for (int k = 1; k < 16; ++k) merge_ms(m, s, lm[k][t], lsv[k][t]);
    colPM[(size_t)it * MM + j0 + t] = m;
    colPS[(size_t)it * MM + j0 + t] = s;
  }
}

// ---- K2: merge stripe partials -> global stats (R10 EXACT) ----
__global__ __launch_bounds__(256) void k_merge(const float* __restrict__ rowPM,
                                               const float* __restrict__ rowPS,
                                               const float* __restrict__ colPM,
                                               const float* __restrict__ colPS,
                                               float* __restrict__ rowM,
                                               float* __restrict__ rowS,
                                               float* __restrict__ colM,
                                               float* __restrict__ colS) {
  int g = blockIdx.x * 256 + threadIdx.x;
  if (g < NN) {
    float m = rowPM[g], s = rowPS[g];
#pragma unroll
    for (int k = 1; k < NTJ; ++k)
      merge_ms(m, s, rowPM[(size_t)k * NN + g], rowPS[(size_t)k * NN + g]);
    rowM[g] = m;
    rowS[g] = s;
  } else {
    int c = g - NN;
    float m = colPM[c], s = colPS[c];
#pragma unroll
    for (int k = 1; k < NTI; ++k)
      merge_ms(m, s, colPM[(size_t)k * MM + c], colPS[(size_t)k * MM + c]);
    colM[c] = m;
    colS[c] = s;
  }
}

// ---- K3: weighted accumulation, 256 blocks x 4 rows, PRE-MERGED stats ----
// (R14's k_macc minus the duplicated col-merge: reads colM/colS once.)
__global__ __launch_bounds__(256) void k_accum(const float* __restrict__ S,
                                               const float* __restrict__ rowM,
                                               const float* __restrict__ rowS,
                                               const float* __restrict__ colM,
                                               const float* __restrict__ colS,
                                               float* __restrict__ bNum,
                                               float* __restrict__ bDen) {
  const int bid = blockIdx.x;  // rows [bid*4, bid*4+4)
  const int t = threadIdx.x;

  float4 cm = reinterpret_cast<const float4*>(colM)[t];
  float4 cs = reinterpret_cast<const float4*>(colS)[t];
  float4 ci;
  ci.x = 1.f / cs.x; ci.y = 1.f / cs.y; ci.z = 1.f / cs.z; ci.w = 1.f / cs.w;

  __shared__ float rowMl[4], rowIl[4];
  if (t < 4) {
    int r = bid * 4 + t;
    rowMl[t] = rowM[r];
    rowIl[t] = 1.f / rowS[r];
  }
  __syncthreads();

  float num = 0.f, den = 0.f;
#pragma unroll
  for (int rl = 0; rl < 4; ++rl) {
    int row = bid * 4 + rl;
    float4 v = reinterpret_cast<const float4*>(S + (size_t)row * MM)[t];
    float rm = rowMl[rl], ri = rowIl[rl];
#define DO_COMP(VX, CMX, CIX)                 \
    {                                         \
      float a = __expf((VX) - rm) * ri;       \
      float b = __expf((VX) - (CMX)) * (CIX); \
      float w = a + b - a * b;                \
      num += w * (VX);                        \
      den += w;                               \
    }
    DO_COMP(v.x, cm.x, ci.x)
    DO_COMP(v.y, cm.y, ci.y)
    DO_COMP(v.z, cm.z, ci.z)
    DO_COMP(v.w, cm.w, ci.w)
#undef DO_COMP
  }

  num = wredSum(num);
  den = wredSum(den);
  __shared__ float rn[4], rd[4];
  const int lane = t & 63, wv = t >> 6;
  if (lane == 0) { rn[wv] = num; rd[wv] = den; }
  __syncthreads();
  if (t == 0) {
    bNum[bid] = rn[0] + rn[1] + rn[2] + rn[3];
    bDen[bid] = rd[0] + rd[1] + rd[2] + rd[3];
  }
}

// ---- K4: final reduce + divide (256 partials, one per thread) ----
__global__ __launch_bounds__(256) void k_final(const float* __restrict__ bNum,
                                               const float* __restrict__ bDen,
                                               float* __restrict__ out) {
  const int t = threadIdx.x;
  float n = bNum[t];
  float d = bDen[t];
  n = wredSum(n);
  d = wredSum(d);
  __shared__ float rn[4], rd[4];
  const int lane = t & 63, wv = t >> 6;
  if (lane == 0) { rn[wv] = n; rd[wv] = d; }
  __syncthreads();
  if (t == 0) out[0] = (rn[0] + rn[1] + rn[2] + rn[3]) / (rd[0] + rd[1] + rd[2] + rd[3]);
}

// ---------------- launch ----------------
extern "C" void kernel_launch(void* const* d_in, const int* in_sizes, int n_in,
                              void* d_out, int out_size, void* d_ws, size_t ws_size,
                              hipStream_t stream) {
  const float* zx = (const float*)d_in[0];
  const float* zy = (const float*)d_in[1];
  float* out = (float*)d_out;

  float* ws = (float*)d_ws;
  float* S     = ws;                        // 1M floats
  float* rowPM = S + (size_t)NN * MM;       // NTJ x NN
  float* rowPS = rowPM + NTJ * NN;
  float* colPM = rowPS + NTJ * NN;          // NTI x MM
  float* colPS = colPM + NTI * MM;
  float* rowM  = colPS + NTI * MM;
  float* rowS  = rowM + NN;
  float* colM  = rowS + NN;
  float* colS  = colM + MM;
  float* bNum  = colS + MM;                 // 256
  float* bDen  = bNum + 256;                // 256

  k_tile<<<dim3(NTJ, NTI), 256, 0, stream>>>(zx, zy, S, rowPM, rowPS, colPM, colPS);
  k_merge<<<8, 256, 0, stream>>>(rowPM, rowPS, colPM, colPS, rowM, rowS, colM, colS);
  k_accum<<<256, 256, 0, stream>>>(S, rowM, rowS, colM, colS, bNum, bDen);
  k_final<<<1, 256, 0, stream>>>(bNum, bDen, out);
}